// Round 11
// baseline (64.211 us; speedup 1.0000x reference)
//
#include <hip/hip_runtime.h>

// Problem constants
#define B_  32
#define L_  2048
#define D_  256
#define T_  64
#define KW  3

typedef float f32x4 __attribute__((ext_vector_type(4)));
typedef short s16x8 __attribute__((ext_vector_type(8)));
typedef short s16x4 __attribute__((ext_vector_type(4)));

__device__ __forceinline__ short f2bf(float f) {
    unsigned u = __builtin_bit_cast(unsigned, f);
    u += 0x7FFFu + ((u >> 16) & 1u);          // round-to-nearest-even
    return (short)(u >> 16);
}

// ---------------------------------------------------------------------------
// fused prep (one launch):
//  bx <  16 : CbfPk = bf16(C) packed in att-kernel B-fragment order
//  bx >= 16 : kcPk = packed relu(C@W+b) in main2 B-fragment order
// ---------------------------------------------------------------------------
__global__ __launch_bounds__(256) void prep_kernel(const float* __restrict__ C,
                                                   const float* __restrict__ W,
                                                   const float* __restrict__ bias,
                                                   short* __restrict__ CbfPk,
                                                   short* __restrict__ kcPk) {
    __shared__ float Ws[256 * 16];
    const int tid = threadIdx.x;

    if (blockIdx.x < 16) {
        const int i0 = (blockIdx.x * 256 + tid) * 4;
        const int t = i0 >> 8, d = i0 & 255;
        const f32x4 v = *(const f32x4*)(C + i0);
        s16x4 s;
        s[0] = f2bf(v[0]); s[1] = f2bf(v[1]); s[2] = f2bf(v[2]); s[3] = f2bf(v[3]);
        const int tt = t >> 4, c = t & 15, ks = d >> 5, gg = (d >> 3) & 3, e = d & 7;
        *(s16x4*)&CbfPk[(((tt * 8 + ks) * 4 + gg) * 16 + c) * 8 + e] = s;
        return;
    }

    const int nb = blockIdx.x - 16;
    const int n0 = nb * 16;

    for (int idx = tid; idx < 256 * 16; idx += 256) {
        const int dd = idx >> 4, nl = idx & 15;
        Ws[idx] = W[dd * (KW * D_) + n0 + nl];
    }
    __syncthreads();

    const int t  = tid >> 2;
    const int nl = tid & 3;
    float acc[4];
    #pragma unroll
    for (int i = 0; i < 4; ++i) acc[i] = bias[n0 + nl + 4 * i];

    const float* Crow = C + t * D_;
    for (int dd = 0; dd < D_; ++dd) {
        const float cv = Crow[dd];
        #pragma unroll
        for (int i = 0; i < 4; ++i)
            acc[i] = fmaf(cv, Ws[dd * 16 + nl + 4 * i], acc[i]);
    }
    const int ks = t >> 5, gg = (t >> 3) & 3, e = t & 7;
    #pragma unroll
    for (int i = 0; i < 4; ++i) {
        const int cc = nl + 4 * i;
        kcPk[(((nb * 2 + ks) * 4 + gg) * 16 + cc) * 8 + e] = f2bf(fmaxf(acc[i], 0.f));
    }
}

// ---------------------------------------------------------------------------
// K1: att[b, l-tile] = bf16(x) @ C^T, output in PACKED A-fragment layout:
//   attPk[tile*1024 + (q*64 + g*16 + c)*8 + e] = att[row=c][t=q*32+g*8+e]
//   tile = b*(L/16) + l/16.
// Per block: 32 rows of one batch, 4 waves (wave w: rows (w&1)*16.., t-tiles
// (w>>1)*2..). No halo. 2 barriers.
// ---------------------------------------------------------------------------
#define K1XST 264
#define K1ATS 72

__global__ __launch_bounds__(256, 7) void att_kernel(const float* __restrict__ x,
                                                     const short* __restrict__ CbfPk,
                                                     short* __restrict__ attPk) {
    __shared__ short xs[32 * K1XST];      // 16896 B
    __shared__ short atts[32 * K1ATS];    //  4608 B

    const int tid  = threadIdx.x;
    const int w    = tid >> 6;
    const int lane = tid & 63;
    const int c    = lane & 15;
    const int g    = lane >> 4;
    const int l0   = blockIdx.x * 32;
    const int b    = blockIdx.y;

    // ---- stage 32 rows as bf16 (exactly 8 passes, coalesced) ----
    const f32x4* x4 = (const f32x4*)(x + (size_t)b * L_ * D_);
    #pragma unroll
    for (int k = 0; k < 8; ++k) {
        const int idx = tid + k * 256;
        const int row = idx >> 6;
        const int d4  = idx & 63;
        const f32x4 v = x4[(size_t)(l0 + row) * 64 + d4];
        s16x4 s;
        s[0] = f2bf(v[0]); s[1] = f2bf(v[1]); s[2] = f2bf(v[2]); s[3] = f2bf(v[3]);
        *(s16x4*)&xs[row * K1XST + d4 * 4] = s;
    }
    __syncthreads();

    // ---- MFMA: wave w = rows m*16.., t-tiles tp*2, tp*2+1 ----
    {
        const int m  = w & 1;
        const int tp = w >> 1;
        f32x4 acc0 = (f32x4){0.f, 0.f, 0.f, 0.f};
        f32x4 acc1 = (f32x4){0.f, 0.f, 0.f, 0.f};
        const short* xr = &xs[(m * 16 + c) * K1XST];
        #pragma unroll
        for (int ks = 0; ks < 8; ++ks) {
            const s16x8 a   = *(const s16x8*)&xr[ks * 32 + g * 8];
            const s16x8 cb0 = *(const s16x8*)&CbfPk[((((tp * 2 + 0) * 8 + ks) * 4 + g) * 16 + c) * 8];
            const s16x8 cb1 = *(const s16x8*)&CbfPk[((((tp * 2 + 1) * 8 + ks) * 4 + g) * 16 + c) * 8];
            acc0 = __builtin_amdgcn_mfma_f32_16x16x32_bf16(a, cb0, acc0, 0, 0, 0);
            acc1 = __builtin_amdgcn_mfma_f32_16x16x32_bf16(a, cb1, acc1, 0, 0, 0);
        }
        // D layout: col=c (t within tile), row=g*4+r
        #pragma unroll
        for (int r = 0; r < 4; ++r) {
            atts[(m * 16 + g * 4 + r) * K1ATS + (tp * 2 + 0) * 16 + c] = f2bf(acc0[r]);
            atts[(m * 16 + g * 4 + r) * K1ATS + (tp * 2 + 1) * 16 + c] = f2bf(acc1[r]);
        }
    }
    __syncthreads();

    // ---- pack-store: 256 chunks of 16 B, fully coalesced ----
    {
        const int pm = tid >> 7;          // which 16-row tile
        const int ck = tid & 127;         // chunk within tile
        const int q  = ck >> 6;
        const int ln = ck & 63;
        const int g2 = ln >> 4;
        const int c2 = ln & 15;
        const s16x8 v = *(const s16x8*)&atts[(pm * 16 + c2) * K1ATS + q * 32 + g2 * 8];
        const size_t tile = (size_t)b * (L_ / 16) + blockIdx.x * 2 + pm;
        *(s16x8*)&attPk[tile * 1024 + ck * 8] = v;
    }
}

// ---------------------------------------------------------------------------
// K2: out = windowed-fold( (att @ kc), x ). No cross-wave data dependency:
//  A-frags read directly from packed attPk; x staged once (f32) for the fold;
//  ONE barrier. Per block: 32 rows (2 16-row subtiles m), wave w owns d-range
//  [w*64, w*64+64); B-frags loaded once per dtl, reused for both m.
// ---------------------------------------------------------------------------
#define XSF 260

__global__ __launch_bounds__(256, 4) void main2_kernel(const float* __restrict__ x,
                                                       const short* __restrict__ attPk,
                                                       const short* __restrict__ kcPk,
                                                       float* __restrict__ out) {
    __shared__ float xsf[34 * XSF];       // 35360 B

    const int tid  = threadIdx.x;
    const int w    = tid >> 6;
    const int lane = tid & 63;
    const int c    = lane & 15;
    const int g    = lane >> 4;
    const int l0   = blockIdx.x * 32;
    const int b    = blockIdx.y;

    // ---- A-frags straight from packed att (wave-contiguous 1 KB reads) ----
    const size_t t0 = ((size_t)b * (L_ / 16) + blockIdx.x * 2) * 1024;
    const s16x8 am00 = *(const s16x8*)&attPk[t0 + (0 * 64 + lane) * 8];
    const s16x8 am01 = *(const s16x8*)&attPk[t0 + (1 * 64 + lane) * 8];
    const s16x8 am10 = *(const s16x8*)&attPk[t0 + 1024 + (0 * 64 + lane) * 8];
    const s16x8 am11 = *(const s16x8*)&attPk[t0 + 1024 + (1 * 64 + lane) * 8];

    // ---- stage x rows l0-1 .. l0+32 as raw f32 (fold only) ----
    const f32x4* x4 = (const f32x4*)(x + (size_t)b * L_ * D_);
    #pragma unroll
    for (int k = 0; k < 9; ++k) {
        const int idx = tid + k * 256;
        if (idx < 34 * 64) {
            const int row = idx >> 6;
            const int d4  = idx & 63;
            const int l   = l0 - 1 + row;
            f32x4 v = (l >= 0 && l < L_) ? x4[(size_t)l * 64 + d4]
                                         : (f32x4){0.f, 0.f, 0.f, 0.f};
            *(f32x4*)&xsf[row * XSF + d4 * 4] = v;
        }
    }
    __syncthreads();

    const size_t outBase = ((size_t)b * L_ + l0) * D_;

    #pragma unroll
    for (int dtl = 0; dtl < 4; ++dtl) {
        const int dcol = w * 64 + dtl * 16 + c;
        const int nbb  = w * 4 + dtl;        // nb = j*16 + nbb
        const s16x8 b0 = *(const s16x8*)&kcPk[((((0 * 16 + nbb) * 2 + 0) * 4 + g) * 16 + c) * 8];
        const s16x8 b1 = *(const s16x8*)&kcPk[((((0 * 16 + nbb) * 2 + 1) * 4 + g) * 16 + c) * 8];
        const s16x8 b2 = *(const s16x8*)&kcPk[((((1 * 16 + nbb) * 2 + 0) * 4 + g) * 16 + c) * 8];
        const s16x8 b3 = *(const s16x8*)&kcPk[((((1 * 16 + nbb) * 2 + 1) * 4 + g) * 16 + c) * 8];
        const s16x8 b4 = *(const s16x8*)&kcPk[((((2 * 16 + nbb) * 2 + 0) * 4 + g) * 16 + c) * 8];
        const s16x8 b5 = *(const s16x8*)&kcPk[((((2 * 16 + nbb) * 2 + 1) * 4 + g) * 16 + c) * 8];

        #pragma unroll
        for (int m = 0; m < 2; ++m) {
            const s16x8 af0 = m ? am10 : am00;
            const s16x8 af1 = m ? am11 : am01;
            f32x4 a0 = (f32x4){0.f,0.f,0.f,0.f};
            f32x4 a1 = (f32x4){0.f,0.f,0.f,0.f};
            f32x4 a2 = (f32x4){0.f,0.f,0.f,0.f};
            a0 = __builtin_amdgcn_mfma_f32_16x16x32_bf16(af0, b0, a0, 0, 0, 0);
            a0 = __builtin_amdgcn_mfma_f32_16x16x32_bf16(af1, b1, a0, 0, 0, 0);
            a1 = __builtin_amdgcn_mfma_f32_16x16x32_bf16(af0, b2, a1, 0, 0, 0);
            a1 = __builtin_amdgcn_mfma_f32_16x16x32_bf16(af1, b3, a1, 0, 0, 0);
            a2 = __builtin_amdgcn_mfma_f32_16x16x32_bf16(af0, b4, a2, 0, 0, 0);
            a2 = __builtin_amdgcn_mfma_f32_16x16x32_bf16(af1, b5, a2, 0, 0, 0);

            // fold: out[l,d] = sum_j ki_j[l,d]*x[l-1+j,d]; xsf row 0 = l0-1
            float xv[6];
            #pragma unroll
            for (int i = 0; i < 6; ++i)
                xv[i] = xsf[(m * 16 + g * 4 + i) * XSF + dcol];

            #pragma unroll
            for (int r = 0; r < 4; ++r) {
                const float o = a0[r] * xv[r] + a1[r] * xv[r + 1] + a2[r] * xv[r + 2];
                out[outBase + (size_t)(m * 16 + g * 4 + r) * D_ + dcol] = o;
            }
        }
    }
}

// ---------------------------------------------------------------------------
extern "C" void kernel_launch(void* const* d_in, const int* in_sizes, int n_in,
                              void* d_out, int out_size, void* d_ws, size_t ws_size,
                              hipStream_t stream) {
    const float* x    = (const float*)d_in[0];
    const float* C    = (const float*)d_in[1];
    const float* Wden = (const float*)d_in[2];
    const float* bden = (const float*)d_in[3];
    float* out = (float*)d_out;

    short* kcPk  = (short*)d_ws;                        // 49152 shorts
    short* CbfPk = (short*)d_ws + KW * D_ * T_;         // 16384 shorts
    short* attPk = CbfPk + T_ * D_;                     // B*(L/16)*1024 shorts = 8.4 MB

    prep_kernel<<<dim3(64), dim3(256), 0, stream>>>(C, Wden, bden, CbfPk, kcPk);

    att_kernel<<<dim3(L_ / 32, B_), dim3(256), 0, stream>>>(x, CbfPk, attPk);

    main2_kernel<<<dim3(L_ / 32, B_), dim3(256), 0, stream>>>(x, attPk, kcPk, out);
}